// Round 9
// baseline (339.637 us; speedup 1.0000x reference)
//
#include <hip/hip_runtime.h>
#include <math.h>
#include <stdint.h>

#define BB 2
#define TT 4
#define NQ 576
#define NKV 576
#define DD 1024
#define HH 16
#define DH 64
#define BT (BB*TT)          // 8
#define NTOK (BT*NQ)        // 4608
#define NPAIR ((size_t)BT*NQ*NKV)   // 2654208
#define NEGV (-(3.402823466e38f) * 0.5f)   // == np.finfo(f32).min / 2, exact

typedef __attribute__((ext_vector_type(8))) short short8v;
typedef __attribute__((ext_vector_type(4))) float f32x4;

__device__ inline ushort f2bf(float f) {
    union { float f; uint32_t u; } v; v.f = f;
    return (ushort)((v.u + 0x7FFFu + ((v.u >> 16) & 1u)) >> 16);
}

__device__ inline void gld_lds16(const ushort* g, ushort* l) {
    __builtin_amdgcn_global_load_lds(
        (const __attribute__((address_space(1))) unsigned int*)g,
        (__attribute__((address_space(3))) unsigned int*)l, 16, 0, 0);
}

// ---------------------------------------------------------------------------
// Fused prep kernel: blocks [0,4608) = prior/flag; [4608,17920) = f2bf x6;
// [17920,19072) = cos/sin tables. One launch instead of three.
// ---------------------------------------------------------------------------
#define S4 ((int)((size_t)NTOK * DD / 4))     // 1179648
#define W4 ((int)((size_t)DD * DD / 4))       // 262144
#define PRIOR_BLKS NTOK                        // 4608
#define F2BF_BLKS ((2 * S4 + 4 * W4) / 256)    // 13312
#define CS_BLKS ((2 * NTOK * 32) / 256)        // 1152

__global__ __launch_bounds__(256) void prep_kernel(
    const float* __restrict__ cq, const float* __restrict__ ck,
    const uint8_t* __restrict__ qm_raw, const uint8_t* __restrict__ km_raw,
    const float* __restrict__ q_tokens, const float* __restrict__ kv_tokens,
    const float* __restrict__ Wq, const float* __restrict__ Wk,
    const float* __restrict__ Wv, const float* __restrict__ Wo,
    const float* __restrict__ f0, const float* __restrict__ f1,
    const float* __restrict__ f2,
    float* __restrict__ prior, uint8_t* __restrict__ flagb,
    ushort* __restrict__ dst0,
    float2* __restrict__ csq, float2* __restrict__ csk)
{
    const int tid = threadIdx.x;
    const int B = blockIdx.x;
    if (B < PRIOR_BLKS) {
        // ---- prior/flag for one (bt,q) row; mask-encoding detect (R3-verified)
        __shared__ int flag_s;
        if (tid == 0) flag_s = 0;
        __syncthreads();
        int local = 0;
        for (int j = tid; j < NTOK; j += 256) {
            if ((j & 3) != 0 && (qm_raw[j] | km_raw[j])) local = 1;
        }
        if (local) atomicOr(&flag_s, 1);
        __syncthreads();
        const int is_u8 = flag_s;
        const int bq = B;
        const int bt = bq / NQ;
        uint8_t qmv = is_u8 ? qm_raw[bq] : (uint8_t)(((const int*)qm_raw)[bq] != 0);
        const float qy = cq[bq * 3 + 1], qx = cq[bq * 3 + 2];
        for (int kv = tid; kv < NKV; kv += 256) {
            const int kb = bt * NKV + kv;
            uint8_t kmv = is_u8 ? km_raw[kb] : (uint8_t)(((const int*)km_raw)[kb] != 0);
            const float ky = ck[kb * 3 + 1], kx = ck[kb * 3 + 2];
            float dy = __fsub_rn(qy, ky);
            float dx = __fsub_rn(qx, kx);
            float d2 = __fadd_rn(__fmul_rn(dy, dy), __fmul_rn(dx, dx));
            float dist = __fsqrt_rn(d2);
            int fl = (dist > 0.5f) | qmv | kmv;
            size_t o = (size_t)bq * NKV + kv;
            prior[o] = __expf(-10.f * dist);
            flagb[o] = (uint8_t)fl;
        }
    } else if (B < PRIOR_BLKS + F2BF_BLKS) {
        // ---- segmented fp32->bf16 (dst regions contiguous from dst0)
        int i = (B - PRIOR_BLKS) * 256 + tid;
        const float* src; int off;
        if (i < 2 * S4) {
            src = (i < S4) ? q_tokens : kv_tokens;
            off = (i < S4) ? i : i - S4;
        } else {
            int j = i - 2 * S4;
            int w = j >> 18;                      // W4 = 2^18
            src = (w == 0) ? Wq : (w == 1) ? Wk : (w == 2) ? Wv : Wo;
            off = j & (W4 - 1);
        }
        float4 v = ((const float4*)src)[off];
        ushort4 o;
        o.x = f2bf(v.x); o.y = f2bf(v.y); o.z = f2bf(v.z); o.w = f2bf(v.w);
        ((ushort4*)dst0)[i] = o;
    } else {
        // ---- cos/sin tables (R3-verified)
        const int PER = NTOK * 32;
        int idx = (B - PRIOR_BLKS - F2BF_BLKS) * 256 + tid;
        int half = idx / PER;
        int r = idx - half * PER;
        int i = r & 31;
        int tok = r >> 5;
        int axis; float f;
        if (i < 12)      { axis = 0; f = f0[i];      }
        else if (i < 22) { axis = 1; f = f1[i - 12]; }
        else             { axis = 2; f = f2[i - 22]; }
        const float* C = half ? ck : cq;
        float c = C[tok * 3 + axis];
        float arg = __fmul_rn(__fmul_rn(1.57079632679489662f, c), f);
        float s, co;
        __sincosf(arg, &s, &co);
        float2 out; out.x = co; out.y = s;
        (half ? csk : csq)[tok * 32 + i] = out;
    }
}

// ---------------------------------------------------------------------------
// GEMM epilogue (shared): modes 1/3/4/5 as R8 (verified)
// ---------------------------------------------------------------------------
__device__ __forceinline__ void gemm_epilogue(
    const float* __restrict__ bias, void* __restrict__ O,
    const float2* __restrict__ cst, const int mode,
    const int gr0, const int gc, f32x4 c)
{
    const float bv_ = bias[gc];
    if (mode == 1) {
#pragma unroll
        for (int i = 0; i < 4; i++)
            ((float*)O)[(size_t)(gr0 + i) * DD + gc] = c[i] + bv_;
    } else if (mode == 3) {
        int bt = gr0 / NQ, nn0 = gr0 - bt * NQ;   // 4-row groups never cross bt
        int h = gc >> 6, dh = gc & 63;
        ushort4 o4;
        o4.x = f2bf(c[0] + bv_); o4.y = f2bf(c[1] + bv_);
        o4.z = f2bf(c[2] + bv_); o4.w = f2bf(c[3] + bv_);
        *(ushort4*)&((ushort*)O)[(((size_t)(bt * HH + h)) * DH + dh) * NQ + nn0] = o4;
    } else {
        int h = gc >> 6, dh = gc & 63;
        int i2 = dh >> 1;
#pragma unroll
        for (int i = 0; i < 4; i++) {
            int tok = gr0 + i;
            float v = c[i] + bv_;
            float vp = __shfl_xor(v, 1);
            float2 cs = cst[tok * 32 + i2];
            float o = (gc & 1) ? (v * cs.x + vp * cs.y)
                               : (v * cs.x - vp * cs.y);
            int bt = tok / NQ, nn = tok - bt * NQ;
            ((ushort*)O)[(((size_t)(bt * HH + h)) * NQ + nn) * DH + dh] = f2bf(o);
        }
    }
}

// ---------------------------------------------------------------------------
// Fused Q/K/V projection GEMM: BM=BN=128, BK=64 (m97 structure). 864 blocks;
// nt = L&7 -> natural XCD round-robin keeps each W n-panel XCD-local.
// T2 slot-swizzle via pre-swizzled global source; gld_lds width-16.
// ---------------------------------------------------------------------------
__global__ __launch_bounds__(256) void gemm_proj3_kernel(
    const ushort* __restrict__ qtb, const ushort* __restrict__ ktb,
    const ushort* __restrict__ Wqb, const ushort* __restrict__ Wkb,
    const ushort* __restrict__ Wvb,
    const float* __restrict__ bq, const float* __restrict__ bk,
    const float* __restrict__ bv,
    ushort* __restrict__ Qh, ushort* __restrict__ Kh, ushort* __restrict__ Vtg,
    const float2* __restrict__ csq, const float2* __restrict__ csk)
{
    __shared__ ushort As[128 * 64];
    __shared__ ushort Bs[128 * 64];
    const int L = blockIdx.x;                 // 864 = 108 m-tiles * 8 n-tiles
    const int mt_g = L >> 3, nt = L & 7;
    const int seg = mt_g / 36;                // 0=Q 1=K 2=V (36*128 = 4608)
    const int m0 = (mt_g - seg * 36) * 128, n0 = nt * 128;
    const ushort* X = (seg == 0) ? qtb : ktb;
    const ushort* W = (seg == 0) ? Wqb : (seg == 1) ? Wkb : Wvb;
    const float* bias = (seg == 0) ? bq : (seg == 1) ? bk : bv;
    void* O = (seg == 0) ? (void*)Qh : (seg == 1) ? (void*)Kh : (void*)Vtg;
    const float2* cst = (seg == 0) ? csq : csk;
    const int mode = (seg == 0) ? 4 : (seg == 1) ? 5 : 3;

    const int tid = threadIdx.x;
    const int lane = tid & 63, w = tid >> 6;
    const int wm = (w >> 1) * 64, wn = (w & 1) * 64;
    const int frow = lane & 15, quad = lane >> 4;
    const int srow = lane >> 3;
    const int scole = ((lane & 7) ^ srow) << 3;

    f32x4 acc[4][4];
#pragma unroll
    for (int m = 0; m < 4; m++)
#pragma unroll
        for (int n = 0; n < 4; n++) acc[m][n] = (f32x4)0.f;

    for (int k0 = 0; k0 < DD; k0 += 64) {
        __syncthreads();
#pragma unroll
        for (int j = 0; j < 4; j++) {
            int c = w * 4 + j;
            gld_lds16(&X[(size_t)(m0 + c * 8 + srow) * DD + k0 + scole], &As[c * 512]);
            gld_lds16(&W[(size_t)(n0 + c * 8 + srow) * DD + k0 + scole], &Bs[c * 512]);
        }
        __syncthreads();
        const int rsw = (frow & 7) << 3;
#pragma unroll
        for (int ks = 0; ks < 2; ks++) {
            short8v a[4], b[4];
#pragma unroll
            for (int m = 0; m < 4; m++)
                a[m] = *(const short8v*)&As[(wm + m * 16 + frow) * 64 + ((ks * 32 + quad * 8) ^ rsw)];
#pragma unroll
            for (int n = 0; n < 4; n++)
                b[n] = *(const short8v*)&Bs[(wn + n * 16 + frow) * 64 + ((ks * 32 + quad * 8) ^ rsw)];
#pragma unroll
            for (int m = 0; m < 4; m++)
#pragma unroll
                for (int n = 0; n < 4; n++)
                    acc[m][n] = __builtin_amdgcn_mfma_f32_16x16x32_bf16(
                        a[m], b[n], acc[m][n], 0, 0, 0);
        }
    }
#pragma unroll
    for (int m = 0; m < 4; m++) {
        const int gr0 = m0 + wm + m * 16 + quad * 4;
#pragma unroll
        for (int n = 0; n < 4; n++)
            gemm_epilogue(bias, O, cst, mode, gr0, n0 + wn + n * 16 + frow, acc[m][n]);
    }
}

// ---------------------------------------------------------------------------
// Output GEMM: BM=64,BN=128 (R8-verified structure), 576 blocks, XCD m-chunks.
// ---------------------------------------------------------------------------
__global__ __launch_bounds__(256) void gemm_out_kernel(
    const ushort* __restrict__ Yh, const ushort* __restrict__ Wob,
    const float* __restrict__ bo, float* __restrict__ out)
{
    __shared__ ushort As[64 * 64];
    __shared__ ushort Bs[128 * 64];
    const int L = blockIdx.x;                 // 576 = 8 * 72
    const int xcd = L & 7, j = L >> 3;
    const int m0 = (xcd * 9 + (j >> 3)) * 64, n0 = (j & 7) * 128;

    const int tid = threadIdx.x;
    const int lane = tid & 63, w = tid >> 6;
    const int wm = (w & 1) * 32, wn = (w >> 1) * 64;
    const int frow = lane & 15, quad = lane >> 4;
    const int srow = lane >> 3;
    const int scole = ((lane & 7) ^ srow) << 3;

    f32x4 acc[2][4];
#pragma unroll
    for (int m = 0; m < 2; m++)
#pragma unroll
        for (int n = 0; n < 4; n++) acc[m][n] = (f32x4)0.f;

    for (int k0 = 0; k0 < DD; k0 += 64) {
        __syncthreads();
#pragma unroll
        for (int j2 = 0; j2 < 2; j2++) {
            int c = w * 2 + j2;
            gld_lds16(&Yh[(size_t)(m0 + c * 8 + srow) * DD + k0 + scole], &As[c * 512]);
        }
#pragma unroll
        for (int j2 = 0; j2 < 4; j2++) {
            int c = w * 4 + j2;
            gld_lds16(&Wob[(size_t)(n0 + c * 8 + srow) * DD + k0 + scole], &Bs[c * 512]);
        }
        __syncthreads();
        const int rsw = (frow & 7) << 3;
#pragma unroll
        for (int ks = 0; ks < 2; ks++) {
            short8v a[2], b[4];
#pragma unroll
            for (int m = 0; m < 2; m++)
                a[m] = *(const short8v*)&As[(wm + m * 16 + frow) * 64 + ((ks * 32 + quad * 8) ^ rsw)];
#pragma unroll
            for (int n = 0; n < 4; n++)
                b[n] = *(const short8v*)&Bs[(wn + n * 16 + frow) * 64 + ((ks * 32 + quad * 8) ^ rsw)];
#pragma unroll
            for (int m = 0; m < 2; m++)
#pragma unroll
                for (int n = 0; n < 4; n++)
                    acc[m][n] = __builtin_amdgcn_mfma_f32_16x16x32_bf16(
                        a[m], b[n], acc[m][n], 0, 0, 0);
        }
    }
#pragma unroll
    for (int m = 0; m < 2; m++) {
        const int gr0 = m0 + wm + m * 16 + quad * 4;
#pragma unroll
        for (int n = 0; n < 4; n++) {
            const int gc = n0 + wn + n * 16 + frow;
            const float bv_ = bo[gc];
            f32x4 c = acc[m][n];
#pragma unroll
            for (int i = 0; i < 4; i++)
                out[(size_t)(gr0 + i) * DD + gc] = c[i] + bv_;
        }
    }
}

// ---------------------------------------------------------------------------
// Barrier-free MFMA flash attention. K/V fragments read DIRECTLY from global
// (XCD-local L2/L1) -- no K/V LDS, no __syncthreads. Only wave-private Ps
// transpose uses LDS (11.3 KB). 24 waves/CU co-resident; pure TLP hiding.
// ---------------------------------------------------------------------------
__global__ __launch_bounds__(256) void attn_mfma_kernel(
    const ushort* __restrict__ Qh, const ushort* __restrict__ Kh,
    const ushort* __restrict__ Vtg,
    const float* __restrict__ prior, const uint8_t* __restrict__ flagb,
    const float* __restrict__ alpha, ushort* __restrict__ Yh)
{
    __shared__ ushort Ps[4][16][88];     // per-wave [q][kv]

    const int tid = threadIdx.x;
    const int lane = tid & 63, w = tid >> 6;
    const int quad = lane >> 4, l15 = lane & 15;

    const int L = blockIdx.x;            // 1152 = 8 XCD * 144
    const int xcd = L & 7;
    const int logical = xcd * 144 + (L >> 3);
    const int bh = logical / 9;          // bt = bh>>4 == xcd
    const int qt = logical - bh * 9;
    const int bt = bh >> 4, h = bh & 15;
    const int q0 = qt * 64;

    const size_t hb = ((size_t)(bt * HH + h)) * NQ * DH;
    const size_t vbs = ((size_t)(bt * HH + h)) * DH * NQ;
    const int qg = q0 + w * 16 + l15;

    const ushort* qrow = Qh + hb + (size_t)qg * DH;
    short8v qf0 = *(const short8v*)(qrow + quad * 8);
    short8v qf1 = *(const short8v*)(qrow + 32 + quad * 8);

    const float alph = alpha[h];
    const size_t pbase = ((size_t)(bt * NQ + qg)) * NKV + quad * 4;

    // prior/flag register prefetch (tile 0)
    float4 prf[4]; uint32_t pfl[4];
#pragma unroll
    for (int jt = 0; jt < 4; jt++) {
        prf[jt] = *(const float4*)&prior[pbase + jt * 16];
        pfl[jt] = *(const uint32_t*)&flagb[pbase + jt * 16];
    }

    float m_run = -INFINITY, l_run = 0.f;
    f32x4 oacc[4];
#pragma unroll
    for (int i = 0; i < 4; i++) oacc[i] = (f32x4)0.f;

    for (int kt = 0; kt < 9; kt++) {
        const int k0 = kt * 64;

        // QK^T: A-frag = K rows direct from global (row=kv=jt*16+l15, k=quad*8+e)
        f32x4 sc[4];
#pragma unroll
        for (int jt = 0; jt < 4; jt++) sc[jt] = (f32x4)0.f;
#pragma unroll
        for (int jt = 0; jt < 4; jt++) {
            const ushort* krow = Kh + hb + (size_t)(k0 + jt * 16 + l15) * DH;
            short8v kf0 = *(const short8v*)(krow + quad * 8);
            short8v kf1 = *(const short8v*)(krow + 32 + quad * 8);
            sc[jt] = __builtin_amdgcn_mfma_f32_16x16x32_bf16(kf0, qf0, sc[jt], 0, 0, 0);
            sc[jt] = __builtin_amdgcn_mfma_f32_16x16x32_bf16(kf1, qf1, sc[jt], 0, 0, 0);
        }

        // bias from prefetched regs; issue next tile's prior prefetch after use
        float p[16];
        float mloc = -INFINITY;
#pragma unroll
        for (int jt = 0; jt < 4; jt++) {
#pragma unroll
            for (int r = 0; r < 4; r++) {
                float prv = (r == 0) ? prf[jt].x : (r == 1) ? prf[jt].y
                          : (r == 2) ? prf[jt].z : prf[jt].w;
                uint8_t fl = (uint8_t)(pfl[jt] >> (8 * r));
                float s = sc[jt][r] * 0.125f + (fl ? NEGV : alph * prv);
                p[jt * 4 + r] = s;
                mloc = fmaxf(mloc, s);
            }
        }
        if (kt < 8) {
            const size_t nb = pbase + (size_t)(kt + 1) * 64;
#pragma unroll
            for (int jt = 0; jt < 4; jt++) {
                prf[jt] = *(const float4*)&prior[nb + jt * 16];
                pfl[jt] = *(const uint32_t*)&flagb[nb + jt * 16];
            }
        }
        mloc = fmaxf(mloc, __shfl_xor(mloc, 16));
        mloc = fmaxf(mloc, __shfl_xor(mloc, 32));
        float m_new = fmaxf(m_run, mloc);
        float scale = __expf(m_run - m_new);    // first iter: exp(-inf)=0
        float psum = 0.f;
#pragma unroll
        for (int i = 0; i < 16; i++) {
            float pv = __expf(p[i] - m_new);    // all-NEG row -> uniform
            p[i] = pv;
            psum += pv;
        }
        psum += __shfl_xor(psum, 16);
        psum += __shfl_xor(psum, 32);
        l_run = l_run * scale + psum;
        m_run = m_new;

        float sr[4];
#pragma unroll
        for (int r = 0; r < 4; r++) sr[r] = __shfl(scale, quad * 4 + r);
#pragma unroll
        for (int tdh = 0; tdh < 4; tdh++)
#pragma unroll
            for (int r = 0; r < 4; r++) oacc[tdh][r] *= sr[r];

        // P -> LDS bf16 transpose to [q][kv] (wave-private; no barrier needed)
#pragma unroll
        for (int jt = 0; jt < 4; jt++) {
#pragma unroll
            for (int rp = 0; rp < 2; rp++) {
                uint32_t pk = (uint32_t)f2bf(p[jt * 4 + 2 * rp]) |
                              ((uint32_t)f2bf(p[jt * 4 + 2 * rp + 1]) << 16);
                *(uint32_t*)&Ps[w][l15][jt * 16 + quad * 4 + 2 * rp] = pk;
            }
        }
        short8v pa0 = *(const short8v*)&Ps[w][l15][quad * 8];
        short8v pa1 = *(const short8v*)&Ps[w][l15][32 + quad * 8];

        // PV: B-frag = Vt rows direct from global (col=dh=tdh*16+l15, k=kv)
#pragma unroll
        for (int tdh = 0; tdh < 4; tdh++) {
            const ushort* vrow = Vtg + vbs + (size_t)(tdh * 16 + l15) * NQ + k0;
            short8v vb0 = *(const short8v*)(vrow + quad * 8);
            short8v vb1 = *(const short8v*)(vrow + 32 + quad * 8);
            oacc[tdh] = __builtin_amdgcn_mfma_f32_16x16x32_bf16(pa0, vb0, oacc[tdh], 0, 0, 0);
            oacc[tdh] = __builtin_amdgcn_mfma_f32_16x16x32_bf16(pa1, vb1, oacc[tdh], 0, 0, 0);
        }
    }

    float linv = 1.0f / l_run;
    float li[4];
#pragma unroll
    for (int r = 0; r < 4; r++) li[r] = __shfl(linv, quad * 4 + r);
#pragma unroll
    for (int tdh = 0; tdh < 4; tdh++) {
#pragma unroll
        for (int r = 0; r < 4; r++) {
            int tok = bt * NQ + q0 + w * 16 + quad * 4 + r;
            Yh[(size_t)tok * DD + h * DH + tdh * 16 + l15] = f2bf(oacc[tdh][r] * li[r]);
        }
    }
}

// ---------------------------------------------------------------------------
extern "C" void kernel_launch(void* const* d_in, const int* in_sizes, int n_in,
                              void* d_out, int out_size, void* d_ws, size_t ws_size,
                              hipStream_t stream)
{
    const float*   q_tokens  = (const float*)d_in[0];
    const float*   kv_tokens = (const float*)d_in[1];
    const float*   coords_q  = (const float*)d_in[2];
    const float*   coords_k  = (const float*)d_in[3];
    const uint8_t* q_pad     = (const uint8_t*)d_in[4];
    const uint8_t* kv_pad    = (const uint8_t*)d_in[5];
    const float*   Wq = (const float*)d_in[6];
    const float*   bq = (const float*)d_in[7];
    const float*   Wk = (const float*)d_in[8];
    const float*   bk = (const float*)d_in[9];
    const float*   Wv = (const float*)d_in[10];
    const float*   bv = (const float*)d_in[11];
    const float*   Wo = (const float*)d_in[12];
    const float*   bo = (const float*)d_in[13];
    const float*   alpha = (const float*)d_in[14];
    const float*   f0 = (const float*)d_in[15];
    const float*   f1 = (const float*)d_in[16];
    const float*   f2 = (const float*)d_in[17];
    float* out = (float*)d_out;

    const size_t SZ = (size_t)NTOK * DD;     // 4718592
    const size_t WSZ = (size_t)DD * DD;      // 1048576
    float2*  csq  = (float2*)d_ws;
    float2*  csk  = csq + (size_t)NTOK * 32;
    float*   prior = (float*)(csk + (size_t)NTOK * 32);
    ushort*  qtb  = (ushort*)(prior + NPAIR);
    ushort*  ktb  = qtb + SZ;
    ushort*  Wqb  = ktb + SZ;
    ushort*  Wkb  = Wqb + WSZ;
    ushort*  Wvb  = Wkb + WSZ;
    ushort*  Wob  = Wvb + WSZ;
    ushort*  Qh   = Wob + WSZ;
    ushort*  Kh   = Qh + SZ;
    ushort*  Vtg  = Kh + SZ;
    ushort*  Yh   = Vtg + SZ;
    uint8_t* flagb = (uint8_t*)(Yh + SZ);

    prep_kernel<<<PRIOR_BLKS + F2BF_BLKS + CS_BLKS, 256, 0, stream>>>(
        coords_q, coords_k, q_pad, kv_pad,
        q_tokens, kv_tokens, Wq, Wk, Wv, Wo, f0, f1, f2,
        prior, flagb, qtb, csq, csk);

    gemm_proj3_kernel<<<864, 256, 0, stream>>>(
        qtb, ktb, Wqb, Wkb, Wvb, bq, bk, bv, Qh, Kh, Vtg, csq, csk);

    attn_mfma_kernel<<<1152, 256, 0, stream>>>(
        Qh, Kh, Vtg, prior, flagb, alpha, Yh);

    gemm_out_kernel<<<576, 256, 0, stream>>>(Yh, Wob, bo, out);
}

// Round 10
// 259.956 us; speedup vs baseline: 1.3065x; 1.3065x over previous
//
#include <hip/hip_runtime.h>
#include <math.h>
#include <stdint.h>

#define BB 2
#define TT 4
#define NQ 576
#define NKV 576
#define DD 1024
#define HH 16
#define DH 64
#define BT (BB*TT)          // 8
#define NTOK (BT*NQ)        // 4608
#define NPAIR ((size_t)BT*NQ*NKV)   // 2654208
#define NEGV (-(3.402823466e38f) * 0.5f)   // == np.finfo(f32).min / 2, exact

typedef __attribute__((ext_vector_type(8))) short short8v;
typedef __attribute__((ext_vector_type(4))) float f32x4;

__device__ inline ushort f2bf(float f) {
    union { float f; uint32_t u; } v; v.f = f;
    return (ushort)((v.u + 0x7FFFu + ((v.u >> 16) & 1u)) >> 16);
}

__device__ inline void gld_lds16(const ushort* g, ushort* l) {
    __builtin_amdgcn_global_load_lds(
        (const __attribute__((address_space(1))) unsigned int*)g,
        (__attribute__((address_space(3))) unsigned int*)l, 16, 0, 0);
}

// ---------------------------------------------------------------------------
// Fused prep kernel (R9-verified): prior/flag + f2bf x6 + cos/sin in one launch
// ---------------------------------------------------------------------------
#define S4 ((int)((size_t)NTOK * DD / 4))     // 1179648
#define W4 ((int)((size_t)DD * DD / 4))       // 262144
#define PRIOR_BLKS NTOK                        // 4608
#define F2BF_BLKS ((2 * S4 + 4 * W4) / 256)    // 13312
#define CS_BLKS ((2 * NTOK * 32) / 256)        // 1152

__global__ __launch_bounds__(256) void prep_kernel(
    const float* __restrict__ cq, const float* __restrict__ ck,
    const uint8_t* __restrict__ qm_raw, const uint8_t* __restrict__ km_raw,
    const float* __restrict__ q_tokens, const float* __restrict__ kv_tokens,
    const float* __restrict__ Wq, const float* __restrict__ Wk,
    const float* __restrict__ Wv, const float* __restrict__ Wo,
    const float* __restrict__ f0, const float* __restrict__ f1,
    const float* __restrict__ f2,
    float* __restrict__ prior, uint8_t* __restrict__ flagb,
    ushort* __restrict__ dst0,
    float2* __restrict__ csq, float2* __restrict__ csk)
{
    const int tid = threadIdx.x;
    const int B = blockIdx.x;
    if (B < PRIOR_BLKS) {
        __shared__ int flag_s;
        if (tid == 0) flag_s = 0;
        __syncthreads();
        int local = 0;
        for (int j = tid; j < NTOK; j += 256) {
            if ((j & 3) != 0 && (qm_raw[j] | km_raw[j])) local = 1;
        }
        if (local) atomicOr(&flag_s, 1);
        __syncthreads();
        const int is_u8 = flag_s;
        const int bq = B;
        const int bt = bq / NQ;
        uint8_t qmv = is_u8 ? qm_raw[bq] : (uint8_t)(((const int*)qm_raw)[bq] != 0);
        const float qy = cq[bq * 3 + 1], qx = cq[bq * 3 + 2];
        for (int kv = tid; kv < NKV; kv += 256) {
            const int kb = bt * NKV + kv;
            uint8_t kmv = is_u8 ? km_raw[kb] : (uint8_t)(((const int*)km_raw)[kb] != 0);
            const float ky = ck[kb * 3 + 1], kx = ck[kb * 3 + 2];
            float dy = __fsub_rn(qy, ky);
            float dx = __fsub_rn(qx, kx);
            float d2 = __fadd_rn(__fmul_rn(dy, dy), __fmul_rn(dx, dx));
            float dist = __fsqrt_rn(d2);
            int fl = (dist > 0.5f) | qmv | kmv;
            size_t o = (size_t)bq * NKV + kv;
            prior[o] = __expf(-10.f * dist);
            flagb[o] = (uint8_t)fl;
        }
    } else if (B < PRIOR_BLKS + F2BF_BLKS) {
        int i = (B - PRIOR_BLKS) * 256 + tid;
        const float* src; int off;
        if (i < 2 * S4) {
            src = (i < S4) ? q_tokens : kv_tokens;
            off = (i < S4) ? i : i - S4;
        } else {
            int j = i - 2 * S4;
            int w = j >> 18;                      // W4 = 2^18
            src = (w == 0) ? Wq : (w == 1) ? Wk : (w == 2) ? Wv : Wo;
            off = j & (W4 - 1);
        }
        float4 v = ((const float4*)src)[off];
        ushort4 o;
        o.x = f2bf(v.x); o.y = f2bf(v.y); o.z = f2bf(v.z); o.w = f2bf(v.w);
        ((ushort4*)dst0)[i] = o;
    } else {
        const int PER = NTOK * 32;
        int idx = (B - PRIOR_BLKS - F2BF_BLKS) * 256 + tid;
        int half = idx / PER;
        int r = idx - half * PER;
        int i = r & 31;
        int tok = r >> 5;
        int axis; float f;
        if (i < 12)      { axis = 0; f = f0[i];      }
        else if (i < 22) { axis = 1; f = f1[i - 12]; }
        else             { axis = 2; f = f2[i - 22]; }
        const float* C = half ? ck : cq;
        float c = C[tok * 3 + axis];
        float arg = __fmul_rn(__fmul_rn(1.57079632679489662f, c), f);
        float s, co;
        __sincosf(arg, &s, &co);
        float2 out; out.x = co; out.y = s;
        (half ? csk : csq)[tok * 32 + i] = out;
    }
}

// ---------------------------------------------------------------------------
// GEMM epilogue (R8/R9-verified): modes 1/3/4/5
// ---------------------------------------------------------------------------
__device__ __forceinline__ void gemm_epilogue(
    const float* __restrict__ bias, void* __restrict__ O,
    const float2* __restrict__ cst, const int mode,
    const int gr0, const int gc, f32x4 c)
{
    const float bv_ = bias[gc];
    if (mode == 1) {
#pragma unroll
        for (int i = 0; i < 4; i++)
            ((float*)O)[(size_t)(gr0 + i) * DD + gc] = c[i] + bv_;
    } else if (mode == 3) {
        int bt = gr0 / NQ, nn0 = gr0 - bt * NQ;   // 4-row groups never cross bt
        int h = gc >> 6, dh = gc & 63;
        ushort4 o4;
        o4.x = f2bf(c[0] + bv_); o4.y = f2bf(c[1] + bv_);
        o4.z = f2bf(c[2] + bv_); o4.w = f2bf(c[3] + bv_);
        *(ushort4*)&((ushort*)O)[(((size_t)(bt * HH + h)) * DH + dh) * NQ + nn0] = o4;
    } else {
        int h = gc >> 6, dh = gc & 63;
        int i2 = dh >> 1;
#pragma unroll
        for (int i = 0; i < 4; i++) {
            int tok = gr0 + i;
            float v = c[i] + bv_;
            float vp = __shfl_xor(v, 1);
            float2 cs = cst[tok * 32 + i2];
            float o = (gc & 1) ? (v * cs.x + vp * cs.y)
                               : (v * cs.x - vp * cs.y);
            int bt = tok / NQ, nn = tok - bt * NQ;
            ((ushort*)O)[(((size_t)(bt * HH + h)) * NQ + nn) * DH + dh] = f2bf(o);
        }
    }
}

// ---------------------------------------------------------------------------
// Fused Q/K/V projection GEMM (R9-verified): BM=BN=128, BK=64, 864 blocks.
// ---------------------------------------------------------------------------
__global__ __launch_bounds__(256) void gemm_proj3_kernel(
    const ushort* __restrict__ qtb, const ushort* __restrict__ ktb,
    const ushort* __restrict__ Wqb, const ushort* __restrict__ Wkb,
    const ushort* __restrict__ Wvb,
    const float* __restrict__ bq, const float* __restrict__ bk,
    const float* __restrict__ bv,
    ushort* __restrict__ Qh, ushort* __restrict__ Kh, ushort* __restrict__ Vtg,
    const float2* __restrict__ csq, const float2* __restrict__ csk)
{
    __shared__ ushort As[128 * 64];
    __shared__ ushort Bs[128 * 64];
    const int L = blockIdx.x;                 // 864 = 108 m-tiles * 8 n-tiles
    const int mt_g = L >> 3, nt = L & 7;
    const int seg = mt_g / 36;                // 0=Q 1=K 2=V
    const int m0 = (mt_g - seg * 36) * 128, n0 = nt * 128;
    const ushort* X = (seg == 0) ? qtb : ktb;
    const ushort* W = (seg == 0) ? Wqb : (seg == 1) ? Wkb : Wvb;
    const float* bias = (seg == 0) ? bq : (seg == 1) ? bk : bv;
    void* O = (seg == 0) ? (void*)Qh : (seg == 1) ? (void*)Kh : (void*)Vtg;
    const float2* cst = (seg == 0) ? csq : csk;
    const int mode = (seg == 0) ? 4 : (seg == 1) ? 5 : 3;

    const int tid = threadIdx.x;
    const int lane = tid & 63, w = tid >> 6;
    const int wm = (w >> 1) * 64, wn = (w & 1) * 64;
    const int frow = lane & 15, quad = lane >> 4;
    const int srow = lane >> 3;
    const int scole = ((lane & 7) ^ srow) << 3;

    f32x4 acc[4][4];
#pragma unroll
    for (int m = 0; m < 4; m++)
#pragma unroll
        for (int n = 0; n < 4; n++) acc[m][n] = (f32x4)0.f;

    for (int k0 = 0; k0 < DD; k0 += 64) {
        __syncthreads();
#pragma unroll
        for (int j = 0; j < 4; j++) {
            int c = w * 4 + j;
            gld_lds16(&X[(size_t)(m0 + c * 8 + srow) * DD + k0 + scole], &As[c * 512]);
            gld_lds16(&W[(size_t)(n0 + c * 8 + srow) * DD + k0 + scole], &Bs[c * 512]);
        }
        __syncthreads();
        const int rsw = (frow & 7) << 3;
#pragma unroll
        for (int ks = 0; ks < 2; ks++) {
            short8v a[4], b[4];
#pragma unroll
            for (int m = 0; m < 4; m++)
                a[m] = *(const short8v*)&As[(wm + m * 16 + frow) * 64 + ((ks * 32 + quad * 8) ^ rsw)];
#pragma unroll
            for (int n = 0; n < 4; n++)
                b[n] = *(const short8v*)&Bs[(wn + n * 16 + frow) * 64 + ((ks * 32 + quad * 8) ^ rsw)];
#pragma unroll
            for (int m = 0; m < 4; m++)
#pragma unroll
                for (int n = 0; n < 4; n++)
                    acc[m][n] = __builtin_amdgcn_mfma_f32_16x16x32_bf16(
                        a[m], b[n], acc[m][n], 0, 0, 0);
        }
    }
#pragma unroll
    for (int m = 0; m < 4; m++) {
        const int gr0 = m0 + wm + m * 16 + quad * 4;
#pragma unroll
        for (int n = 0; n < 4; n++)
            gemm_epilogue(bias, O, cst, mode, gr0, n0 + wn + n * 16 + frow, acc[m][n]);
    }
}

// ---------------------------------------------------------------------------
// Output GEMM (R8-verified): BM=64,BN=128, 576 blocks, XCD m-chunks.
// ---------------------------------------------------------------------------
__global__ __launch_bounds__(256) void gemm_out_kernel(
    const ushort* __restrict__ Yh, const ushort* __restrict__ Wob,
    const float* __restrict__ bo, float* __restrict__ out)
{
    __shared__ ushort As[64 * 64];
    __shared__ ushort Bs[128 * 64];
    const int L = blockIdx.x;                 // 576 = 8 * 72
    const int xcd = L & 7, j = L >> 3;
    const int m0 = (xcd * 9 + (j >> 3)) * 64, n0 = (j & 7) * 128;

    const int tid = threadIdx.x;
    const int lane = tid & 63, w = tid >> 6;
    const int wm = (w & 1) * 32, wn = (w >> 1) * 64;
    const int frow = lane & 15, quad = lane >> 4;
    const int srow = lane >> 3;
    const int scole = ((lane & 7) ^ srow) << 3;

    f32x4 acc[2][4];
#pragma unroll
    for (int m = 0; m < 2; m++)
#pragma unroll
        for (int n = 0; n < 4; n++) acc[m][n] = (f32x4)0.f;

    for (int k0 = 0; k0 < DD; k0 += 64) {
        __syncthreads();
#pragma unroll
        for (int j2 = 0; j2 < 2; j2++) {
            int c = w * 2 + j2;
            gld_lds16(&Yh[(size_t)(m0 + c * 8 + srow) * DD + k0 + scole], &As[c * 512]);
        }
#pragma unroll
        for (int j2 = 0; j2 < 4; j2++) {
            int c = w * 4 + j2;
            gld_lds16(&Wob[(size_t)(n0 + c * 8 + srow) * DD + k0 + scole], &Bs[c * 512]);
        }
        __syncthreads();
        const int rsw = (frow & 7) << 3;
#pragma unroll
        for (int ks = 0; ks < 2; ks++) {
            short8v a[2], b[4];
#pragma unroll
            for (int m = 0; m < 2; m++)
                a[m] = *(const short8v*)&As[(wm + m * 16 + frow) * 64 + ((ks * 32 + quad * 8) ^ rsw)];
#pragma unroll
            for (int n = 0; n < 4; n++)
                b[n] = *(const short8v*)&Bs[(wn + n * 16 + frow) * 64 + ((ks * 32 + quad * 8) ^ rsw)];
#pragma unroll
            for (int m = 0; m < 2; m++)
#pragma unroll
                for (int n = 0; n < 4; n++)
                    acc[m][n] = __builtin_amdgcn_mfma_f32_16x16x32_bf16(
                        a[m], b[n], acc[m][n], 0, 0, 0);
        }
    }
#pragma unroll
    for (int m = 0; m < 2; m++) {
        const int gr0 = m0 + wm + m * 16 + quad * 4;
#pragma unroll
        for (int n = 0; n < 4; n++) {
            const int gc = n0 + wn + n * 16 + frow;
            const float bv_ = bo[gc];
            f32x4 c = acc[m][n];
#pragma unroll
            for (int i = 0; i < 4; i++)
                out[(size_t)(gr0 + i) * DD + gc] = c[i] + bv_;
        }
    }
}

// ---------------------------------------------------------------------------
// MFMA flash attention — R8-verified version (57.8 µs): LDS-staged K/V with
// T14 reg prefetch, prior/flag reg prefetch, XCD swizzle (bt == xcd).
// ---------------------------------------------------------------------------
__global__ __launch_bounds__(256) void attn_mfma_kernel(
    const ushort* __restrict__ Qh, const ushort* __restrict__ Kh,
    const ushort* __restrict__ Vtg,
    const float* __restrict__ prior, const uint8_t* __restrict__ flagb,
    const float* __restrict__ alpha, ushort* __restrict__ Yh)
{
    __shared__ ushort Ks[64][72];        // [kv][dh]
    __shared__ ushort Vt[64][72];        // [dh][kv]
    __shared__ ushort Ps[4][16][88];     // per-wave [q][kv]

    const int tid = threadIdx.x;
    const int lane = tid & 63, w = tid >> 6;
    const int quad = lane >> 4, l15 = lane & 15;

    const int L = blockIdx.x;            // 1152 = 8 XCD * 144
    const int xcd = L & 7;
    const int logical = xcd * 144 + (L >> 3);
    const int bh = logical / 9;          // bt = bh>>4 == xcd
    const int qt = logical - bh * 9;
    const int bt = bh >> 4, h = bh & 15;
    const int q0 = qt * 64;

    const size_t hb = ((size_t)(bt * HH + h)) * NQ * DH;
    const size_t vbs = ((size_t)(bt * HH + h)) * DH * NQ;
    const int qg = q0 + w * 16 + l15;

    const ushort* qrow = Qh + hb + (size_t)qg * DH;
    short8v qf0 = *(const short8v*)(qrow + quad * 8);
    short8v qf1 = *(const short8v*)(qrow + 32 + quad * 8);

    const float alph = alpha[h];
    const size_t pbase = ((size_t)(bt * NQ + qg)) * NKV + quad * 4;

    const int krow = tid >> 2, kcol = (tid & 3) * 16;
    const ushort* Ksrc = Kh + hb + (size_t)krow * DH + kcol;
    const ushort* Vsrc = Vtg + vbs + (size_t)krow * NQ + kcol;

    short8v ka0 = *(const short8v*)(Ksrc);
    short8v ka1 = *(const short8v*)(Ksrc + 8);
    short8v va0 = *(const short8v*)(Vsrc);
    short8v va1 = *(const short8v*)(Vsrc + 8);
    float4 prf[4]; uint32_t pfl[4];
#pragma unroll
    for (int jt = 0; jt < 4; jt++) {
        prf[jt] = *(const float4*)&prior[pbase + jt * 16];
        pfl[jt] = *(const uint32_t*)&flagb[pbase + jt * 16];
    }

    float m_run = -INFINITY, l_run = 0.f;
    f32x4 oacc[4];
#pragma unroll
    for (int i = 0; i < 4; i++) oacc[i] = (f32x4)0.f;

    for (int kt = 0; kt < 9; kt++) {
        __syncthreads();   // prev tile's LDS reads complete
        *(short8v*)&Ks[krow][kcol]     = ka0;
        *(short8v*)&Ks[krow][kcol + 8] = ka1;
        *(short8v*)&Vt[krow][kcol]     = va0;
        *(short8v*)&Vt[krow][kcol + 8] = va1;
        if (kt < 8) {   // issue next-tile loads; latency hides under compute
            const ushort* nk = Ksrc + (size_t)(kt + 1) * 64 * DH;
            const ushort* nv = Vsrc + (size_t)(kt + 1) * 64;
            ka0 = *(const short8v*)(nk);
            ka1 = *(const short8v*)(nk + 8);
            va0 = *(const short8v*)(nv);
            va1 = *(const short8v*)(nv + 8);
        }
        __syncthreads();   // staged tile visible

        // QK^T: D[kv_local, q]
        f32x4 sc[4];
#pragma unroll
        for (int jt = 0; jt < 4; jt++) sc[jt] = (f32x4)0.f;
#pragma unroll
        for (int jt = 0; jt < 4; jt++) {
            short8v kf0 = *(const short8v*)&Ks[jt * 16 + l15][quad * 8];
            short8v kf1 = *(const short8v*)&Ks[jt * 16 + l15][32 + quad * 8];
            sc[jt] = __builtin_amdgcn_mfma_f32_16x16x32_bf16(kf0, qf0, sc[jt], 0, 0, 0);
            sc[jt] = __builtin_amdgcn_mfma_f32_16x16x32_bf16(kf1, qf1, sc[jt], 0, 0, 0);
        }

        // bias from prefetched regs; then prefetch next tile's prior/flag
        float p[16];
        float mloc = -INFINITY;
#pragma unroll
        for (int jt = 0; jt < 4; jt++) {
#pragma unroll
            for (int r = 0; r < 4; r++) {
                float prv = (r == 0) ? prf[jt].x : (r == 1) ? prf[jt].y
                          : (r == 2) ? prf[jt].z : prf[jt].w;
                uint8_t fl = (uint8_t)(pfl[jt] >> (8 * r));
                float s = sc[jt][r] * 0.125f + (fl ? NEGV : alph * prv);
                p[jt * 4 + r] = s;
                mloc = fmaxf(mloc, s);
            }
        }
        if (kt < 8) {
            const size_t nb = pbase + (size_t)(kt + 1) * 64;
#pragma unroll
            for (int jt = 0; jt < 4; jt++) {
                prf[jt] = *(const float4*)&prior[nb + jt * 16];
                pfl[jt] = *(const uint32_t*)&flagb[nb + jt * 16];
            }
        }
        mloc = fmaxf(mloc, __shfl_xor(mloc, 16));
        mloc = fmaxf(mloc, __shfl_xor(mloc, 32));
        float m_new = fmaxf(m_run, mloc);
        float scale = __expf(m_run - m_new);    // first iter: exp(-inf)=0
        float psum = 0.f;
#pragma unroll
        for (int i = 0; i < 16; i++) {
            float pv = __expf(p[i] - m_new);    // all-NEG row -> uniform
            p[i] = pv;
            psum += pv;
        }
        psum += __shfl_xor(psum, 16);
        psum += __shfl_xor(psum, 32);
        l_run = l_run * scale + psum;
        m_run = m_new;

        float sr[4];
#pragma unroll
        for (int r = 0; r < 4; r++) sr[r] = __shfl(scale, quad * 4 + r);
#pragma unroll
        for (int tdh = 0; tdh < 4; tdh++)
#pragma unroll
            for (int r = 0; r < 4; r++) oacc[tdh][r] *= sr[r];

        // P -> LDS bf16 transpose to [q][kv]
#pragma unroll
        for (int jt = 0; jt < 4; jt++) {
#pragma unroll
            for (int rp = 0; rp < 2; rp++) {
                uint32_t pk = (uint32_t)f2bf(p[jt * 4 + 2 * rp]) |
                              ((uint32_t)f2bf(p[jt * 4 + 2 * rp + 1]) << 16);
                *(uint32_t*)&Ps[w][l15][jt * 16 + quad * 4 + 2 * rp] = pk;
            }
        }
        // wave-private RAW through LDS: compiler inserts lgkmcnt wait

        short8v pa0 = *(const short8v*)&Ps[w][l15][quad * 8];
        short8v pa1 = *(const short8v*)&Ps[w][l15][32 + quad * 8];
#pragma unroll
        for (int tdh = 0; tdh < 4; tdh++) {
            short8v vb0 = *(const short8v*)&Vt[tdh * 16 + l15][quad * 8];
            short8v vb1 = *(const short8v*)&Vt[tdh * 16 + l15][32 + quad * 8];
            oacc[tdh] = __builtin_amdgcn_mfma_f32_16x16x32_bf16(pa0, vb0, oacc[tdh], 0, 0, 0);
            oacc[tdh] = __builtin_amdgcn_mfma_f32_16x16x32_bf16(pa1, vb1, oacc[tdh], 0, 0, 0);
        }
    }

    float linv = 1.0f / l_run;
    float li[4];
#pragma unroll
    for (int r = 0; r < 4; r++) li[r] = __shfl(linv, quad * 4 + r);
#pragma unroll
    for (int tdh = 0; tdh < 4; tdh++) {
#pragma unroll
        for (int r = 0; r < 4; r++) {
            int tok = bt * NQ + q0 + w * 16 + quad * 4 + r;
            Yh[(size_t)tok * DD + h * DH + tdh * 16 + l15] = f2bf(oacc[tdh][r] * li[r]);
        }
    }
}

// ---------------------------------------------------------------------------
extern "C" void kernel_launch(void* const* d_in, const int* in_sizes, int n_in,
                              void* d_out, int out_size, void* d_ws, size_t ws_size,
                              hipStream_t stream)
{
    const float*   q_tokens  = (const float*)d_in[0];
    const float*   kv_tokens = (const float*)d_in[1];
    const float*   coords_q  = (const float*)d_in[2];
    const float*   coords_k  = (const float*)d_in[3];
    const uint8_t* q_pad     = (const uint8_t*)d_in[4];
    const uint8_t* kv_pad    = (const uint8_t*)d_in[5];
    const float*   Wq = (const float*)d_in[6];
    const float*   bq = (const float*)d_in[7];
    const float*   Wk = (const float*)d_in[8];
    const float*   bk = (const float*)d_in[9];
    const float*   Wv = (const float*)d_in[10];
    const float*   bv = (const float*)d_in[11];
    const float*   Wo = (const float*)d_in[12];
    const float*   bo = (const float*)d_in[13];
    const float*   alpha = (const float*)d_in[14];
    const float*   f0 = (const float*)d_in[15];
    const float*   f1 = (const float*)d_in[16];
    const float*   f2 = (const float*)d_in[17];
    float* out = (float*)d_out;

    const size_t SZ = (size_t)NTOK * DD;     // 4718592
    const size_t WSZ = (size_t)DD * DD;      // 1048576
    float2*  csq  = (float2*)d_ws;
    float2*  csk  = csq + (size_t)NTOK * 32;
    float*   prior = (float*)(csk + (size_t)NTOK * 32);
    ushort*  qtb  = (ushort*)(prior + NPAIR);
    ushort*  ktb  = qtb + SZ;
    ushort*  Wqb  = ktb + SZ;
    ushort*  Wkb  = Wqb + WSZ;
    ushort*  Wvb  = Wkb + WSZ;
    ushort*  Wob  = Wvb + WSZ;
    ushort*  Qh   = Wob + WSZ;
    ushort*  Kh   = Qh + SZ;
    ushort*  Vtg  = Kh + SZ;
    ushort*  Yh   = Vtg + SZ;
    uint8_t* flagb = (uint8_t*)(Yh + SZ);

    prep_kernel<<<PRIOR_BLKS + F2BF_BLKS + CS_BLKS, 256, 0, stream>>>(
        coords_q, coords_k, q_pad, kv_pad,
        q_tokens, kv_tokens, Wq, Wk, Wv, Wo, f0, f1, f2,
        prior, flagb, qtb, csq, csk);

    gemm_proj3_kernel<<<864, 256, 0, stream>>>(
        qtb, ktb, Wqb, Wkb, Wvb, bq, bk, bv, Qh, Kh, Vtg, csq, csk);

    attn_mfma_kernel<<<1152, 256, 0, stream>>>(
        Qh, Kh, Vtg, prior, flagb, alpha, Yh);

    gemm_out_kernel<<<576, 256, 0, stream>>>(Yh, Wob, bo, out);
}